// Round 1
// baseline (410.467 us; speedup 1.0000x reference)
//
#include <hip/hip_runtime.h>

#define NN   100000
#define NE   1600000
#define BSH  9            // 512 nodes per bucket
#define BSZ  512
#define NBK  196          // ceil(NN/512)
#define TA   4096         // edges per binA chunk-block
#define NBA  391          // ceil(NE/TA)
#define SCAP 64           // per-(chunk,bucket) slot capacity (mean 20.9 + 9.4 sigma)
#define CAP2 9216         // per-bucket capacity in adj (edges + self-loops)
#define NBG  782          // gemm blocks in k_front
#define NPREP 7           // W2 (4 tiles) + Wc (2 tiles) + W2s/W2d att-fold

typedef _Float16 half_t;
typedef __attribute__((ext_vector_type(2))) _Float16 f16x2;
typedef __attribute__((ext_vector_type(4))) _Float16 f16x4;
typedef __attribute__((ext_vector_type(8))) _Float16 f16x8;
typedef __attribute__((ext_vector_type(4))) float    f32x4;

// ============================ K1: fused front ============================
// blocks [0,782): gemm1 (fp32 X @ fp32 W1 -> H fp16) with att_src/att_dst FOLDED
//                 in as B-columns 128..135 (asrc/adst come out of the MFMA acc,
//                 no shuffle epilogue).
// blocks [782,789): transpose W2/Wc to fp16 [n][k]; block 6 computes W2s/W2d
//                 fold columns into WT2 rows 128..135 (rows 136..143 zero).
// blocks [789,1180): binA role: bin TA edges into fixed per-(chunk,bucket) slots.
__global__ __launch_bounds__(256) void k_front(const float* __restrict__ X, const float* __restrict__ W1,
                                               const float* __restrict__ atts, const float* __restrict__ attd,
                                               half_t* __restrict__ H, float* __restrict__ asrc,
                                               float* __restrict__ adst,
                                               const float* __restrict__ W2, const float* __restrict__ Wc,
                                               const float* __restrict__ atts2, const float* __restrict__ attd2,
                                               half_t* __restrict__ WT2, half_t* __restrict__ WTc,
                                               const int* __restrict__ src, const int* __restrict__ dst,
                                               unsigned int* __restrict__ bpk, int* __restrict__ bh) {
  __shared__ __align__(16) char smem[21760];
  int t = threadIdx.x;
  int bid = blockIdx.x;

  if (bid >= NBG + NPREP) {
    // ---- binA role: fixed-slot binning ----
    int hb = bid - NBG - NPREP;               // chunk-block id [0,391)
    int* hist  = (int*)smem;                  // [196]
    int* hscan = hist + NBK;                  // [196]
    int* cnt   = hscan + NBK;                 // [196]
    int* ssc   = cnt + NBK;                   // [256]
    unsigned int* staged = (unsigned int*)(ssc + 256);  // [4096]
    int e0 = hb * TA;
    if (t < NBK) { hist[t] = 0; cnt[t] = 0; }
    __syncthreads();
#pragma unroll
    for (int i = 0; i < TA / 256; i++) {
      int e = e0 + t + i * 256;
      if (e < NE) atomicAdd(&hist[dst[e] >> BSH], 1);
    }
    __syncthreads();
    // exclusive scan of hist (196 <= 256)
    {
      int v = (t < NBK) ? hist[t] : 0;
      int x = v;
      ssc[t] = x;
      for (int off = 1; off < 256; off <<= 1) {
        __syncthreads();
        int y = (t >= off) ? ssc[t - off] : 0;
        __syncthreads();
        x += y;
        ssc[t] = x;
      }
      if (t < NBK) hscan[t] = x - v;
    }
    __syncthreads();
#pragma unroll
    for (int i = 0; i < TA / 256; i++) {
      int e = e0 + t + i * 256;
      if (e < NE) {
        int d = dst[e];
        int bk = d >> BSH;
        int pos = hscan[bk] + atomicAdd(&cnt[bk], 1);
        staged[pos] = ((unsigned int)src[e] << BSH) | (unsigned int)(d & (BSZ - 1));
      }
    }
    __syncthreads();
    // contiguous flush into fixed slots; write counts (cw <= SCAP=64: single lane-pass)
    int wave = t >> 6, lane = t & 63;
    for (int bk = wave; bk < NBK; bk += 4) {
      int c = hist[bk];
      int cw = min(c, SCAP);
      size_t base = ((size_t)bk * NBA + hb) * SCAP;
      int lo = hscan[bk];
      for (int j = lane; j < cw; j += 64) bpk[base + j] = staged[lo + j];
      if (lane == 0) bh[bk * NBA + hb] = cw;
    }
    return;
  }

  if (bid >= NBG) {
    // ---- weight prep role ----
    int b = bid - NBG;
    if (b == 6) {
      // att-fold columns for layer 2: WT2 rows 128..135 = W2 @ att2 per head; 136..143 zero
      int e = t >> 5, kr = t & 31, h = e & 3;
      const float* att = ((e < 4) ? atts2 : attd2) + h * 32;
#pragma unroll
      for (int u = 0; u < 4; u++) {
        int k = u * 32 + kr;
        const float* wrow = W2 + (size_t)k * 128 + h * 32;
        float s = 0.f;
#pragma unroll
        for (int c = 0; c < 32; c += 4) {
          float4 wv = *(const float4*)(wrow + c);
          float4 av = *(const float4*)(att + c);
          s += wv.x * av.x + wv.y * av.y + wv.z * av.z + wv.w * av.w;
        }
        WT2[(size_t)(128 + e) * 128 + k] = (half_t)s;
      }
      for (int u = t; u < 8 * 128; u += 256) WT2[(size_t)136 * 128 + u] = (half_t)0.f;
      return;
    }
    float (*tile)[65] = (float(*)[65])smem;  // 64x65 fp32 = 16.6KB
    const float* W;
    half_t* WT;
    int k0, n0, N, NTr;
    if (b < 4) { W = W2; WT = WT2; k0 = (b >> 1) * 64; n0 = (b & 1) * 64; N = 128; NTr = 128; }
    else       { int bb = b - 4; W = Wc; WT = WTc; k0 = bb * 64; n0 = 0; N = 40; NTr = 48; }
    int col = t & 63, r4 = t >> 6;
#pragma unroll
    for (int i = 0; i < 16; i++) {
      int row = r4 * 16 + i;                       // k-local
      float v = 0.f;
      if (n0 + col < N) v = W[(size_t)(k0 + row) * N + n0 + col];
      tile[row][col] = v;
    }
    __syncthreads();
#pragma unroll
    for (int i = 0; i < 16; i++) {
      int nrow = r4 * 16 + i;                      // n-local
      if (n0 + nrow < NTr) WT[(size_t)(n0 + nrow) * 128 + k0 + col] = (half_t)tile[col][nrow];
    }
    return;
  }

  // ---- gemm1 role ----
  half_t* Xt = (half_t*)smem;          // [128][40]
  half_t* Wt = Xt + 128 * 40;          // [144][40]: 0..127 W1^T, 128..135 att-fold, 136..143 zero
  int wave = t >> 6, lane = t & 63;
  int l15 = lane & 15, quad = lane >> 4;
  int rb = bid * 128;

  // zero pad rows once (first k-loop barrier orders this before any frag read)
  for (int u = t; u < 8 * 40; u += 256) Wt[136 * 40 + u] = (half_t)0.f;

  f32x4 acc[2][9];
#pragma unroll
  for (int rt = 0; rt < 2; rt++)
#pragma unroll
    for (int ct = 0; ct < 9; ct++) acc[rt][ct] = (f32x4){0.f, 0.f, 0.f, 0.f};

  for (int k0 = 0; k0 < 128; k0 += 32) {
    __syncthreads();
#pragma unroll
    for (int i = 0; i < 4; i++) {
      int lin = i * 256 + t;
      int row = lin >> 3;
      int c4 = (lin & 7) * 4;
      float4 v = make_float4(0.f, 0.f, 0.f, 0.f);
      int gr = rb + row;
      if (gr < NN) v = *(const float4*)(X + (size_t)gr * 128 + k0 + c4);
      f16x4 hv;
      hv[0] = (half_t)v.x; hv[1] = (half_t)v.y; hv[2] = (half_t)v.z; hv[3] = (half_t)v.w;
      *(f16x4*)(Xt + row * 40 + c4) = hv;
    }
#pragma unroll
    for (int i = 0; i < 4; i++) {
      int lin = i * 256 + t;
      int kr = lin >> 5;
      int n4 = (lin & 31) * 4;
      float4 v = *(const float4*)(W1 + (size_t)(k0 + kr) * 128 + n4);
      Wt[(n4 + 0) * 40 + kr] = (half_t)v.x;
      Wt[(n4 + 1) * 40 + kr] = (half_t)v.y;
      Wt[(n4 + 2) * 40 + kr] = (half_t)v.z;
      Wt[(n4 + 3) * 40 + kr] = (half_t)v.w;
    }
    // att-fold rows 128..135: Wt[128+e][kr] = sum_c W1[k0+kr][h*32+c] * att[h][c]
    {
      int e = t >> 5, kr = t & 31, h = e & 3;
      const float* att = ((e < 4) ? atts : attd) + h * 32;
      const float* wrow = W1 + (size_t)(k0 + kr) * 128 + h * 32;
      float s = 0.f;
#pragma unroll
      for (int c = 0; c < 32; c += 4) {
        float4 wv = *(const float4*)(wrow + c);
        float4 av = *(const float4*)(att + c);
        s += wv.x * av.x + wv.y * av.y + wv.z * av.z + wv.w * av.w;
      }
      Wt[(128 + e) * 40 + kr] = (half_t)s;
    }
    __syncthreads();

    f16x8 a0 = *(const f16x8*)(Xt + (wave * 32 + l15) * 40 + quad * 8);
    f16x8 a1 = *(const f16x8*)(Xt + (wave * 32 + 16 + l15) * 40 + quad * 8);
#pragma unroll
    for (int ct = 0; ct < 9; ct++) {
      f16x8 b = *(const f16x8*)(Wt + (ct * 16 + l15) * 40 + quad * 8);
      acc[0][ct] = __builtin_amdgcn_mfma_f32_16x16x32_f16(a0, b, acc[0][ct], 0, 0, 0);
      acc[1][ct] = __builtin_amdgcn_mfma_f32_16x16x32_f16(a1, b, acc[1][ct], 0, 0, 0);
    }
  }

#pragma unroll
  for (int rt = 0; rt < 2; rt++) {
    int rbase = rb + wave * 32 + rt * 16 + quad * 4;
#pragma unroll
    for (int reg = 0; reg < 4; reg++) {
      int row = rbase + reg;
      if (row < NN) {
#pragma unroll
        for (int ct = 0; ct < 8; ct++) {
          H[(size_t)row * 128 + ct * 16 + l15] = (half_t)acc[rt][ct][reg];
        }
        // attention logits from fold columns (cols 128..135)
        if (l15 < 8) {
          float v = acc[rt][8][reg];
          if (l15 < 4) asrc[row * 4 + l15] = v;
          else         adst[row * 4 + (l15 - 4)] = v;
        }
      }
    }
  }
}

// ============================ binB: gather chunks, sort bucket by dst, emit sbeg/send + adj =======
__global__ __launch_bounds__(256) void k_binB(const unsigned int* __restrict__ bpk,
                                              const int* __restrict__ bh,
                                              int* __restrict__ sbeg, int* __restrict__ send,
                                              int* __restrict__ adj) {
  __shared__ int lhist[BSZ];
  __shared__ int lscan[BSZ];
  __shared__ int lcur[BSZ];
  __shared__ int ssc[256];
  __shared__ int carr[NBA];
  __shared__ unsigned int staged[CAP2];
  int b = blockIdx.x;
  int t = threadIdx.x;
  int nbeg = b << BSH;
  int nloc = min(BSZ, NN - nbeg);
  int adjb = b * CAP2;
  // load chunk counts (NBA=391 > 256 -> loop)
  for (int u = t; u < NBA; u += 256) carr[u] = bh[b * NBA + u];
  lhist[2 * t] = (2 * t < nloc) ? 1 : 0;       // self-loop occupies slot 0 of each node's segment
  lhist[2 * t + 1] = (2 * t + 1 < nloc) ? 1 : 0;
  lcur[2 * t] = 1;
  lcur[2 * t + 1] = 1;
  __syncthreads();
  int wave = t >> 6, lane = t & 63;
  // pass 1: histogram by local dst (read chunks from global; c <= 64: single pass)
  for (int a = wave; a < NBA; a += 4) {
    int c = carr[a];
    size_t base = ((size_t)b * NBA + a) * SCAP;
    for (int j = lane; j < c; j += 64) atomicAdd(&lhist[bpk[base + j] & (BSZ - 1)], 1);
  }
  __syncthreads();
  // exclusive scan of 512 with 256 threads
  {
    int v0 = lhist[2 * t], v1 = lhist[2 * t + 1];
    int s2 = v0 + v1;
    int x = s2;
    ssc[t] = x;
    for (int off = 1; off < 256; off <<= 1) {
      __syncthreads();
      int y = (t >= off) ? ssc[t - off] : 0;
      __syncthreads();
      x += y;
      ssc[t] = x;
    }
    int ex = x - s2;
    lscan[2 * t] = ex;
    lscan[2 * t + 1] = ex + v0;
  }
  __syncthreads();
  int total = lscan[BSZ - 1] + lhist[BSZ - 1];
  // per-node CSR bounds + self-loop records
#pragma unroll
  for (int u = 0; u < 2; u++) {
    int i = t + u * 256;
    if (i < nloc) {
      int bg = adjb + lscan[i];
      sbeg[nbeg + i] = bg;
      send[nbeg + i] = bg + lhist[i];
      staged[lscan[i]] = (unsigned int)(nbeg + i);   // self-loop: src = node itself
    }
  }
  __syncthreads();
  // pass 2: scatter edges into sorted staging (slots after the self-loop)
  for (int a = wave; a < NBA; a += 4) {
    int c = carr[a];
    size_t base = ((size_t)b * NBA + a) * SCAP;
    for (int j = lane; j < c; j += 64) {
      unsigned int v = bpk[base + j];
      int dl = v & (BSZ - 1);
      int idx = lscan[dl] + atomicAdd(&lcur[dl], 1);
      if (idx < CAP2) staged[idx] = v >> BSH;
    }
  }
  __syncthreads();
  // contiguous stream-out
  int lim = min(total, CAP2);
  for (int i = t; i < lim; i += 256) adj[adjb + i] = (int)staged[i];
}

// ============================ fused aggregation: 8 edges in flight ============================
// one wave per dst node; 8 lanes x 16ch cover one 256-B row; 8 edge-groups; 1-deep prefetch.
__global__ __launch_bounds__(256) void k_agg(const half_t* __restrict__ H, const int* __restrict__ sbeg,
                                             const int* __restrict__ send, const int* __restrict__ adj,
                                             const float* __restrict__ asrc, const float* __restrict__ adst,
                                             const float* __restrict__ bias, half_t* __restrict__ out) {
  int n = blockIdx.x * 4 + (threadIdx.x >> 6);
  if (n >= NN) return;
  int lane = threadIdx.x & 63;
  int sub = lane & 7;              // 16-channel slice [sub*16, sub*16+16)
  int g = lane >> 3;               // edge group [0,8)
  int head = sub >> 1;
  float ad = adst[(size_t)n * 4 + head];
  float acc[16];
#pragma unroll
  for (int j = 0; j < 16; j++) acc[j] = 0.f;
  float wsum = 0.f;
  int beg = sbeg[n], end = send[n];
  int i = beg + g;
  int s = 0;
  float a = 0.f;
  if (i < end) {
    s = adj[i];
    a = asrc[(size_t)s * 4 + head];
  }
  while (i < end) {
    int inext = i + 8;
    int sn = 0;
    float an = 0.f;
    if (inext < end) {             // prefetch next edge's index + logit
      sn = adj[inext];
      an = asrc[(size_t)sn * 4 + head];
    }
    float ev = a + ad;
    ev = (ev > 0.f) ? ev : 0.2f * ev;
    float w = __expf(ev);
    const f16x8* hp = (const f16x8*)(H + (size_t)s * 128 + sub * 16);
    f16x8 h0 = hp[0], h1 = hp[1];
    wsum += w;
#pragma unroll
    for (int j = 0; j < 8; j++) acc[j] += w * (float)h0[j];
#pragma unroll
    for (int j = 0; j < 8; j++) acc[8 + j] += w * (float)h1[j];
    s = sn; a = an; i = inext;
  }
  // combine the 8 edge-groups (lane bits 3..5)
#pragma unroll
  for (int m = 8; m < 64; m <<= 1) {
    wsum += __shfl_xor(wsum, m, 64);
#pragma unroll
    for (int j = 0; j < 16; j++) acc[j] += __shfl_xor(acc[j], m, 64);
  }
  float scale = 1.0f / (wsum + 1e-16f);
  // lane writes channels sub*16 + g*2, +1 (full 256-B row per wave, coalesced)
  float o0 = acc[0], o1 = acc[1];
#pragma unroll
  for (int r = 1; r < 8; r++) {
    if (g == r) { o0 = acc[2 * r]; o1 = acc[2 * r + 1]; }
  }
  int ch = sub * 16 + g * 2;
  o0 = fmaxf(o0 * scale + bias[ch], 0.f);
  o1 = fmaxf(o1 * scale + bias[ch + 1], 0.f);
  f16x2 o;
  o[0] = (half_t)o0;
  o[1] = (half_t)o1;
  *(f16x2*)(out + (size_t)n * 128 + ch) = o;
}

// ============================ MFMA GEMM (half input, pre-transposed W with fold cols) ============================
__global__ __launch_bounds__(256) void k_gemm_att(const half_t* __restrict__ X, const half_t* __restrict__ WT,
                                                  half_t* __restrict__ H, float* __restrict__ asrc,
                                                  float* __restrict__ adst) {
  __shared__ __align__(16) half_t Xt[128 * 40];
  __shared__ __align__(16) half_t Wt[144 * 40];
  int t = threadIdx.x;
  int wave = t >> 6, lane = t & 63;
  int l15 = lane & 15, quad = lane >> 4;
  int rb = blockIdx.x * 128;

  f32x4 acc[2][9];
#pragma unroll
  for (int rt = 0; rt < 2; rt++)
#pragma unroll
    for (int ct = 0; ct < 9; ct++) acc[rt][ct] = (f32x4){0.f, 0.f, 0.f, 0.f};

  for (int k0 = 0; k0 < 128; k0 += 32) {
    __syncthreads();
#pragma unroll
    for (int i = 0; i < 2; i++) {
      int lin = i * 256 + t;
      int row = lin >> 2;
      int c8 = (lin & 3) * 8;
      f16x8 hv = (f16x8)(half_t)0;
      int gr = rb + row;
      if (gr < NN) hv = *(const f16x8*)(X + (size_t)gr * 128 + k0 + c8);
      *(f16x8*)(Xt + row * 40 + c8) = hv;
    }
#pragma unroll
    for (int i = 0; i < 3; i++) {
      int lin = i * 256 + t;
      if (lin < 576) {                     // 144 rows x 4 chunks
        int row = lin >> 2;
        int c8 = (lin & 3) * 8;
        *(f16x8*)(Wt + row * 40 + c8) = *(const f16x8*)(WT + (size_t)row * 128 + k0 + c8);
      }
    }
    __syncthreads();

    f16x8 a0 = *(const f16x8*)(Xt + (wave * 32 + l15) * 40 + quad * 8);
    f16x8 a1 = *(const f16x8*)(Xt + (wave * 32 + 16 + l15) * 40 + quad * 8);
#pragma unroll
    for (int ct = 0; ct < 9; ct++) {
      f16x8 b = *(const f16x8*)(Wt + (ct * 16 + l15) * 40 + quad * 8);
      acc[0][ct] = __builtin_amdgcn_mfma_f32_16x16x32_f16(a0, b, acc[0][ct], 0, 0, 0);
      acc[1][ct] = __builtin_amdgcn_mfma_f32_16x16x32_f16(a1, b, acc[1][ct], 0, 0, 0);
    }
  }

#pragma unroll
  for (int rt = 0; rt < 2; rt++) {
    int rbase = rb + wave * 32 + rt * 16 + quad * 4;
#pragma unroll
    for (int reg = 0; reg < 4; reg++) {
      int row = rbase + reg;
      if (row < NN) {
#pragma unroll
        for (int ct = 0; ct < 8; ct++) {
          H[(size_t)row * 128 + ct * 16 + l15] = (half_t)acc[rt][ct][reg];
        }
        if (l15 < 8) {
          float v = acc[rt][8][reg];
          if (l15 < 4) asrc[row * 4 + l15] = v;
          else         adst[row * 4 + (l15 - 4)] = v;
        }
      }
    }
  }
}

// ============================ classifier (MFMA, Wc pre-transposed, N padded to 48) ============================
__global__ __launch_bounds__(256) void k_classifier(const half_t* __restrict__ Hf, const half_t* __restrict__ WTc,
                                                    const float* __restrict__ bc, float* __restrict__ out) {
  __shared__ __align__(16) half_t Xt[128 * 40];
  __shared__ __align__(16) half_t Wt[48 * 40];
  int t = threadIdx.x;
  int wave = t >> 6, lane = t & 63;
  int l15 = lane & 15, quad = lane >> 4;
  int rb = blockIdx.x * 128;

  f32x4 acc[2][3];
#pragma unroll
  for (int rt = 0; rt < 2; rt++)
#pragma unroll
    for (int ct = 0; ct < 3; ct++) acc[rt][ct] = (f32x4){0.f, 0.f, 0.f, 0.f};

  for (int k0 = 0; k0 < 128; k0 += 32) {
    __syncthreads();
#pragma unroll
    for (int i = 0; i < 2; i++) {
      int lin = i * 256 + t;
      int row = lin >> 2;
      int c8 = (lin & 3) * 8;
      f16x8 hv = (f16x8)(half_t)0;
      int gr = rb + row;
      if (gr < NN) hv = *(const f16x8*)(Hf + (size_t)gr * 128 + k0 + c8);
      *(f16x8*)(Xt + row * 40 + c8) = hv;
    }
    if (t < 192) {
      int row = t >> 2;
      int c8 = (t & 3) * 8;
      *(f16x8*)(Wt + row * 40 + c8) = *(const f16x8*)(WTc + (size_t)row * 128 + k0 + c8);
    }
    __syncthreads();

    f16x8 a0 = *(const f16x8*)(Xt + (wave * 32 + l15) * 40 + quad * 8);
    f16x8 a1 = *(const f16x8*)(Xt + (wave * 32 + 16 + l15) * 40 + quad * 8);
#pragma unroll
    for (int ct = 0; ct < 3; ct++) {
      f16x8 b = *(const f16x8*)(Wt + (ct * 16 + l15) * 40 + quad * 8);
      acc[0][ct] = __builtin_amdgcn_mfma_f32_16x16x32_f16(a0, b, acc[0][ct], 0, 0, 0);
      acc[1][ct] = __builtin_amdgcn_mfma_f32_16x16x32_f16(a1, b, acc[1][ct], 0, 0, 0);
    }
  }

#pragma unroll
  for (int rt = 0; rt < 2; rt++) {
#pragma unroll
    for (int ct = 0; ct < 3; ct++) {
      int col = ct * 16 + l15;
      if (col < 40) {
        float bv = bc[col];
#pragma unroll
        for (int reg = 0; reg < 4; reg++) {
          int row = rb + wave * 32 + rt * 16 + quad * 4 + reg;
          if (row < NN) out[(size_t)row * 40 + col] = acc[rt][ct][reg] + bv;
        }
      }
    }
  }
}

// ============================ launch ============================

extern "C" void kernel_launch(void* const* d_in, const int* in_sizes, int n_in,
                              void* d_out, int out_size, void* d_ws, size_t ws_size,
                              hipStream_t stream) {
  const float* x   = (const float*)d_in[0];
  const int*   ei  = (const int*)d_in[1];
  const float* W1  = (const float*)d_in[2];
  const float* as1 = (const float*)d_in[3];
  const float* ad1 = (const float*)d_in[4];
  const float* b1  = (const float*)d_in[5];
  const float* W2  = (const float*)d_in[6];
  const float* as2 = (const float*)d_in[7];
  const float* ad2 = (const float*)d_in[8];
  const float* b2  = (const float*)d_in[9];
  const float* Wc  = (const float*)d_in[10];
  const float* bc  = (const float*)d_in[11];
  float* out = (float*)d_out;

  const int* esrc = ei;
  const int* edst = ei + NE;

  char* w = (char*)d_ws;
  auto alloc = [&](size_t bytes) {
    void* p = (void*)w;
    w += (bytes + 255) & ~(size_t)255;
    return p;
  };
  half_t* A   = (half_t*)alloc(sizeof(half_t) * (size_t)NN * 128);  // gather target
  half_t* B   = (half_t*)alloc(sizeof(half_t) * (size_t)NN * 128);  // layer output
  float* asrc = (float*)alloc(sizeof(float) * (size_t)NN * 4);
  float* adst = (float*)alloc(sizeof(float) * (size_t)NN * 4);
  int* sbeg   = (int*)alloc(sizeof(int) * NN);
  int* send   = (int*)alloc(sizeof(int) * NN);
  unsigned int* bpk = (unsigned int*)alloc(sizeof(unsigned int) * (size_t)NBK * NBA * SCAP);
  int* bh     = (int*)alloc(sizeof(int) * NBK * NBA);
  int* adj    = (int*)alloc(sizeof(int) * (size_t)NBK * CAP2);
  half_t* WT2 = (half_t*)alloc(sizeof(half_t) * 144 * 128);
  half_t* WTc = (half_t*)alloc(sizeof(half_t) * 48 * 128);

  // ---- fused front: gemm1(+att fold) + weight prep + fixed-slot edge binning ----
  k_front<<<NBG + NPREP + NBA, 256, 0, stream>>>(x, W1, as1, ad1, A, asrc, adst,
                                                 W2, Wc, as2, ad2, WT2, WTc, esrc, edst, bpk, bh);
  // ---- CSR finalize ----
  k_binB<<<NBK, 256, 0, stream>>>(bpk, bh, sbeg, send, adj);

  // ---- layer 1 aggregate ----
  k_agg<<<(NN + 3) / 4, 256, 0, stream>>>(A, sbeg, send, adj, asrc, adst, b1, B);

  // ---- layer 2 (att fold cols live in WT2 rows 128..143) ----
  k_gemm_att<<<(NN + 127) / 128, 256, 0, stream>>>(B, WT2, A, asrc, adst);
  k_agg<<<(NN + 3) / 4, 256, 0, stream>>>(A, sbeg, send, adj, asrc, adst, b2, B);

  // ---- classifier ----
  k_classifier<<<(NN + 127) / 128, 256, 0, stream>>>(B, WTc, bc, out);
}